// Round 2
// baseline (184.991 us; speedup 1.0000x reference)
//
#include <hip/hip_runtime.h>

#define N_NODES 100000
#define N_EDGES 3200000
#define F_IN    128
#define HID     64
#define NGRAPH  64

#define NBUK    196        // ceil(100000 / 512) buckets of 512 nodes
#define BSHIFT  9
#define BCAP    18432      // mean 16384, sigma ~128 -> +16 sigma
#define CHUNK   5120       // 256 threads x 20 edges; 625 * 5120 == 3.2M exactly
#define NBLK_A  625
#define SLICES  8          // partB slices per bucket
#define NWORDS  3200       // 100000 bits -> 3125 words, padded
#define MAXDEG  96         // in-degree ~Poisson(32); P(>96) ~ 1e-19
#define NIDCAP  4096       // needed nodes ~2100; exactly-once alloc -> no waste
#define L2DEG   8          // big-dst out-edges per needed source (~1 avg, max ~3)
#define NBLK_X  2176       // xaggtrans grid (~1 node per block)

// counters: [2] = nid allocator (init 64: nids 0..63 = big nodes = graph ids)

__device__ __forceinline__ bool is_big(int v, const int* __restrict__ batch) {
    return (v == N_NODES - 1) || (batch[v] != batch[v + 1]);
}
__device__ __forceinline__ float dinv_of(int degv) {
    return rsqrtf((float)(degv + 1));                // +1 self-loop
}

// Fused init (replaces memset + old k_init):
//  - big node of graph g is the graph-end node -> nid = batch[v], no allocator
//  - bigmask/nmask words built via per-wave __ballot + plain word stores
//    (N/32 = 3125 exactly; words >= 3125 stay stale but are NEVER read:
//    all probes/or's use node ids < N)
//  - zeroes deg / counters / bcnt / incnt / l2cnt, seeds out[g] = b2 (added
//    exactly once per graph, matching the reference's +b2 at the big node)
__global__ void k_init(const int* __restrict__ batch, unsigned* __restrict__ bigmask,
                       unsigned* __restrict__ nmask, int* __restrict__ nid_of,
                       int* __restrict__ nlist, int* __restrict__ counters,
                       int* __restrict__ bcnt, int* __restrict__ incnt,
                       int* __restrict__ l2cnt, int* __restrict__ deg,
                       const float* __restrict__ b2, float* __restrict__ out) {
    const int t = threadIdx.x;
    const int bx = blockIdx.x;
    if (bx == 0) {
        if (t < 64) { counters[t] = (t == 2) ? NGRAPH : 0; out[t] = b2[0]; }
        bcnt[t] = 0;                                  // NBUK padded to 256
    } else if (bx <= 16) {
        incnt[(bx - 1) * 256 + t] = 0;                // 4096 ints
    } else if (bx <= 32) {
        l2cnt[(bx - 17) * 256 + t] = 0;               // 4096 ints
    }
    int v = bx * 256 + t;
    bool big = (v < N_NODES) && is_big(v, batch);
    unsigned long long m = __ballot(big);
    if (v < N_NODES) {
        deg[v] = 0;
        int g = big ? batch[v] : -1;
        nid_of[v] = g;
        if (big) nlist[g] = v;
        int lane = t & 63;
        if (lane == 0)  { unsigned w = (unsigned)m;         bigmask[v >> 5] = w; nmask[v >> 5] = w; }
        if (lane == 32) { unsigned w = (unsigned)(m >> 32); bigmask[v >> 5] = w; nmask[v >> 5] = w; }
    }
}

// Pass A: partition 5120 edges/block into 196 dst-range buckets.
// Per-wave hist -> shfl scan (2 barriers) -> LDS scatter -> coalesced write-out.
// Payload packs (src<<9)|(dst&511).
// Fused big-dst handling: atomicOr into nmask[src]; the RETURN VALUE gives an
// exactly-once 0->1 bit transition, so the winner allocates the nid right here
// (plain stores to nid_of/nlist, read only after the kernel boundary).
// NOTE (R1 post-mortem): lazy CAS allocation in partB FAILED — plain nid_of
// reads hit stale non-coherent L1/XCD-L2 lines, 8 slices x ~2.1k nodes
// over-allocate past NIDCAP and edges get dropped. Allocation must be
// exactly-once at the coherence point (this atomicOr) or a dedicated pass.
// NOTE (R12 post-mortem): partA is latency-bound at ~41us across three
// structurally different implementations (direct scatter / staged sort /
// shfl-scan; 625 vs 1250 blocks) — do not re-tune; this is its plateau.
// NOTE (R10 post-mortem): do NOT fuse cross-kernel handoffs with
// __threadfence on gfx950 — device-scope fences drain per-XCD L2;
// kernel boundaries provide the ordering for free.
__global__ __launch_bounds__(256) void k_partA(const int* __restrict__ src,
        const int* __restrict__ dst, const unsigned* __restrict__ bigmask,
        unsigned* __restrict__ nmask, int* __restrict__ nid_of,
        int* __restrict__ nlist, int* __restrict__ counters,
        unsigned* __restrict__ plist, int* __restrict__ bcnt) {
    __shared__ unsigned staged[CHUNK];         // 20480 B, bucket-ordered payload
    __shared__ unsigned char sbkt[CHUNK];      // 5120 B, bucket id per slot
    __shared__ int hist4[4][NBUK];             // 3136 B
    __shared__ int startb[256];                // exclusive starts (NBUK padded)
    __shared__ int curb[NBUK], gbasea[NBUK];
    __shared__ int wsum[4];
    const int t = threadIdx.x;
    const int lane = t & 63;
    const int w = t >> 6;
    for (int i = t; i < NBUK; i += 256) {
        hist4[0][i] = 0; hist4[1][i] = 0; hist4[2][i] = 0; hist4[3][i] = 0;
    }
    __syncthreads();

    const int E0 = blockIdx.x * CHUNK;         // multiple of 4
    const int4* s4 = (const int4*)(src + E0);
    const int4* d4 = (const int4*)(dst + E0);
    int vloc[20]; unsigned pk[20];
#pragma unroll
    for (int it = 0; it < 5; ++it) {
        int4 dd = d4[t + it * 256];
        int4 ss = s4[t + it * 256];
        int vv[4] = {dd.x, dd.y, dd.z, dd.w};
        int uu[4] = {ss.x, ss.y, ss.z, ss.w};
#pragma unroll
        for (int j = 0; j < 4; ++j) {
            int v = vv[j], u = uu[j];
            vloc[it * 4 + j] = v;
            pk[it * 4 + j] = ((unsigned)u << BSHIFT) | (unsigned)(v & 511);
            atomicAdd(&hist4[w][v >> BSHIFT], 1);
            if ((bigmask[v >> 5] >> (v & 31)) & 1) {      // L1-hot 12.8 KB table
                unsigned bit = 1u << (u & 31);
                unsigned old = atomicOr(&nmask[u >> 5], bit);   // ~2k total
                if (!(old & bit)) {                       // first marker wins
                    int p = atomicAdd(&counters[2], 1);   // starts at 64
                    if (p < NIDCAP) { nid_of[u] = p; nlist[p] = u; }
                }
            }
        }
    }
    __syncthreads();
    // bucket counts -> exclusive prefix: shfl scan within wave + cross-wave combine
    int c = 0;
    if (t < NBUK) c = hist4[0][t] + hist4[1][t] + hist4[2][t] + hist4[3][t];
    int sc = c;
#pragma unroll
    for (int off = 1; off < 64; off <<= 1) {
        int y = __shfl_up(sc, off, 64);
        if (lane >= off) sc += y;
    }
    if (lane == 63) wsum[w] = sc;
    __syncthreads();
    int pre = 0;
#pragma unroll
    for (int k = 0; k < 4; ++k) pre += (k < w) ? wsum[k] : 0;
    int excl = pre + sc - c;
    startb[t] = excl;
    if (t < NBUK) {
        curb[t]   = excl;
        gbasea[t] = atomicAdd(&bcnt[t], c);    // reserve global run
    }
    __syncthreads();
#pragma unroll
    for (int it = 0; it < 20; ++it) {          // LDS scatter (cheap)
        int b = vloc[it] >> BSHIFT;
        int pos = atomicAdd(&curb[b], 1);
        staged[pos] = pk[it];
        sbkt[pos]   = (unsigned char)b;
    }
    __syncthreads();
    for (int i = t; i < CHUNK; i += 256) {     // coalesced run write-out
        int b = sbkt[i];
        int s = gbasea[b] + (i - startb[b]);
        if (s < BCAP) plist[(size_t)b * BCAP + s] = staged[i];
    }
}

// Pass B: 8 slices per bucket (1568 blocks). Private 512-bin LDS histogram +
// CSR extraction (nmask probed via L1); coalesced atomic flush into deg[].
// nid_of reads are plain loads: every needed node was assigned in k_init
// (big) or k_partA (marked sources) — kernel boundary makes them coherent.
// Fused: csr2 records big-dst out-edges per SOURCE nid for the layer-2 epilogue.
__global__ __launch_bounds__(256) void k_partB(const unsigned* __restrict__ plist,
        const int* __restrict__ bcnt, const unsigned* __restrict__ nmask,
        const unsigned* __restrict__ bigmask, const int* __restrict__ nid_of,
        int* __restrict__ incnt, int* __restrict__ csr, int* __restrict__ deg,
        int* __restrict__ l2cnt, int* __restrict__ csr2) {
    __shared__ int bins[512];
    const int b = blockIdx.x / SLICES, s = blockIdx.x % SLICES;
    for (int i = threadIdx.x; i < 512; i += 256) bins[i] = 0;
    __syncthreads();
    int n = bcnt[b]; if (n > BCAP) n = BCAP;
    const int i0 = (int)((long)n * s / SLICES);
    const int i1 = (int)((long)n * (s + 1) / SLICES);
    const unsigned* lp = plist + (size_t)b * BCAP;
    const int lo = b << BSHIFT;
    for (int i = i0 + threadIdx.x; i < i1; i += 256) {
        unsigned e = lp[i];
        int local = (int)(e & 511u);
        atomicAdd(&bins[local], 1);
        int v = lo + local;
        if ((nmask[v >> 5] >> (v & 31)) & 1) {           // L1-hot probe, ~2% hit
            int nidv = nid_of[v];
            int u = (int)(e >> BSHIFT);
            if (nidv >= 0) {
                int slot = atomicAdd(&incnt[nidv], 1);   // ~67k over ~2.1k ctrs
                if (slot < MAXDEG) csr[nidv * MAXDEG + slot] = u;
            }
            if ((bigmask[v >> 5] >> (v & 31)) & 1) {     // big dst: layer-2 edge
                int nidu = nid_of[u];
                if (nidu >= 0) {
                    int s2 = atomicAdd(&l2cnt[nidu], 1); // ~2k total
                    if (s2 < L2DEG) csr2[nidu * L2DEG + s2] = v;
                }
            }
        }
    }
    __syncthreads();
    for (int i = threadIdx.x; i < 512; i += 256) {       // coalesced flush
        int v = lo + i, c = bins[i];
        if (c > 0 && v < N_NODES) atomicAdd(&deg[v], c);
    }
}

// Fused: xagg (linearity: aggregate raw x rows) -> @W1 + b1 -> ReLU -> dot W2
// -> layer-2 scatter (csr2 out-edges + self-loop term for big nodes).
// One block per needed node; aggregate lives only in LDS; no h2s array.
__global__ __launch_bounds__(256) void k_xaggtrans(const int* __restrict__ nlist,
        const int* __restrict__ incnt, const int* __restrict__ csr,
        const int* __restrict__ deg, const float* __restrict__ x,
        const float* __restrict__ W1, const float* __restrict__ b1,
        const float* __restrict__ W2, const int* __restrict__ counters,
        const int* __restrict__ l2cnt, const int* __restrict__ csr2,
        const int* __restrict__ batch, float* __restrict__ out) {
    __shared__ float4 sm[8][32];                     // 4 KB partials
    __shared__ float xaggL[F_IN];                    // 512 B aggregate
    __shared__ float p2[4 * HID];                    // 1 KB W1 partials
    int ncnt = counters[2]; if (ncnt > NIDCAP) ncnt = NIDCAP;
    const int tid = threadIdx.x;
    const int l = tid & 31, g = tid >> 5;            // phase-1 roles
    const int f = tid & 63, gg = tid >> 6;           // phase-2 roles
    for (int nid = blockIdx.x; nid < ncnt; nid += gridDim.x) {
        int v = nlist[nid];
        if (v < 0) continue;                         // safety (unused path)
        int m = incnt[nid]; if (m > MAXDEG) m = MAXDEG;
        const int* cs = csr + nid * MAXDEG;
        float4 acc = make_float4(0.f, 0.f, 0.f, 0.f);
        for (int j = g; j < m; j += 8) {
            int u = cs[j];                            // 32-lane broadcast
            float du = dinv_of(deg[u]);
            float4 xr = ((const float4*)(x + (size_t)u * F_IN))[l]; // 512B row
            acc.x += du * xr.x; acc.y += du * xr.y;
            acc.z += du * xr.z; acc.w += du * xr.w;
        }
        sm[g][l] = acc;
        __syncthreads();
        if (tid < 32) {                               // reduce + self-loop term
            float4 tot = make_float4(0.f, 0.f, 0.f, 0.f);
#pragma unroll
            for (int k = 0; k < 8; ++k) {
                float4 p = sm[k][tid];
                tot.x += p.x; tot.y += p.y; tot.z += p.z; tot.w += p.w;
            }
            float dv = dinv_of(deg[v]);
            float4 xv = ((const float4*)(x + (size_t)v * F_IN))[tid];
            float4 r;
            r.x = dv * tot.x + dv * dv * xv.x;
            r.y = dv * tot.y + dv * dv * xv.y;
            r.z = dv * tot.z + dv * dv * xv.z;
            r.w = dv * tot.w + dv * dv * xv.w;
            ((float4*)xaggL)[tid] = r;
        }
        __syncthreads();
        // phase 2: h1[f] = sum_k xaggL[k] * W1[k][f]; 4 k-slices of 32
        float a = 0.f;
#pragma unroll
        for (int k0 = 0; k0 < 32; ++k0) {
            int k = gg * 32 + k0;
            a += xaggL[k] * W1[(size_t)k * HID + f];  // coalesced, L1/L2-hot
        }
        p2[gg * HID + f] = a;
        __syncthreads();
        if (tid < HID) {
            float h = p2[tid] + p2[HID + tid] + p2[2 * HID + tid] + p2[3 * HID + tid] + b1[tid];
            float cc = fmaxf(h, 0.f) * W2[tid];
#pragma unroll
            for (int off = 32; off > 0; off >>= 1) cc += __shfl_down(cc, off, 64);
            if (tid == 0) {
                // fused layer-2 epilogue: ~1 out-edge avg, 64 hot counters
                float du = dinv_of(deg[v]);
                int c2 = l2cnt[nid]; if (c2 > L2DEG) c2 = L2DEG;
                for (int j = 0; j < c2; ++j) {
                    int wv = csr2[nid * L2DEG + j];
                    atomicAdd(&out[batch[wv]], du * dinv_of(deg[wv]) * cc);
                }
                if (nid < NGRAPH)                     // big node: nid == batch[v]
                    atomicAdd(&out[nid], du * du * cc);
            }
        }
        __syncthreads();
    }
}

extern "C" void kernel_launch(void* const* d_in, const int* in_sizes, int n_in,
                              void* d_out, int out_size, void* d_ws, size_t ws_size,
                              hipStream_t stream) {
    const float* x     = (const float*)d_in[0];
    const int*   eidx  = (const int*)d_in[1];
    const int*   src   = eidx;
    const int*   dst   = eidx + N_EDGES;
    const int*   batch = (const int*)d_in[2];
    const float* W1    = (const float*)d_in[3];
    const float* b1    = (const float*)d_in[4];
    const float* W2    = (const float*)d_in[5];
    const float* b2    = (const float*)d_in[6];
    float*       out   = (float*)d_out;

    // ---- workspace layout (no memset: k_init zeroes all consumed state) ----
    char* ws = (char*)d_ws;
    size_t off = 0;
    int*      counters = (int*)(ws + off);      off += 256;
    int*      bcnt     = (int*)(ws + off);      off += 1024;               // NBUK padded
    unsigned* nmask    = (unsigned*)(ws + off); off += NWORDS * 4;         // 12.8 KB
    unsigned* bigmask  = (unsigned*)(ws + off); off += NWORDS * 4;
    int*      incnt    = (int*)(ws + off);      off += NIDCAP * 4;
    int*      l2cnt    = (int*)(ws + off);      off += NIDCAP * 4;
    int*      deg      = (int*)(ws + off);      off += (size_t)N_NODES * 4; // 0.4 MB
    int*      nid_of   = (int*)(ws + off);      off += (size_t)N_NODES * 4;
    int*      nlist    = (int*)(ws + off);      off += (size_t)NIDCAP * 4;
    int*      csr2     = (int*)(ws + off);      off += (size_t)NIDCAP * L2DEG * 4; // 128 KB
    int*      csr      = (int*)(ws + off);      off += (size_t)NIDCAP * MAXDEG * 4; // 1.6 MB
    unsigned* plist    = (unsigned*)(ws + off); off += (size_t)NBUK * BCAP * 4;     // 14.5 MB
    if (off > ws_size) return;  // visible validation failure if ws too small

    const int BN = (N_NODES + 255) / 256;

    k_init<<<BN, 256, 0, stream>>>(batch, bigmask, nmask, nid_of, nlist, counters,
                                   bcnt, incnt, l2cnt, deg, b2, out);
    k_partA<<<NBLK_A, 256, 0, stream>>>(src, dst, bigmask, nmask, nid_of, nlist,
                                        counters, plist, bcnt);
    k_partB<<<NBUK * SLICES, 256, 0, stream>>>(plist, bcnt, nmask, bigmask, nid_of,
                                               incnt, csr, deg, l2cnt, csr2);
    k_xaggtrans<<<NBLK_X, 256, 0, stream>>>(nlist, incnt, csr, deg, x, W1, b1, W2,
                                            counters, l2cnt, csr2, batch, out);
}